// Round 1
// baseline (4914.419 us; speedup 1.0000x reference)
//
#include <hip/hip_runtime.h>
#include <math.h>

#define HIDDEN 4096
#define NHEADS 32
#define HEADDIM 128

// ---------------------------------------------------------------------------
// GEMM (NT): C[M,N] = A[M,K] . B[N,K]^T   (A,B row-major, K contiguous)
// 128x128 block tile, BK=16, 256 threads, 8x8 micro-tile per thread.
// ---------------------------------------------------------------------------
__global__ __launch_bounds__(256)
void gemm_nt(const float* __restrict__ A, const float* __restrict__ B,
             float* __restrict__ C, int M, int N, int K) {
  __shared__ float As[16][128];
  __shared__ float Bs[16][128];
  const int tid = threadIdx.x;
  const int bm = blockIdx.y * 128;
  const int bn = blockIdx.x * 128;
  const int ty = tid >> 4;        // 0..15 (row group)
  const int tx = tid & 15;        // 0..15 (col group)
  const int lrow = tid >> 1;      // 0..127 staging row
  const int lkq  = (tid & 1) * 4; // 0 or 4

  float acc[8][8];
#pragma unroll
  for (int i = 0; i < 8; ++i)
#pragma unroll
    for (int j = 0; j < 8; ++j) acc[i][j] = 0.f;

  const float* Ap = A + (size_t)(bm + lrow) * K + lkq;
  const float* Bp = B + (size_t)(bn + lrow) * K + lkq;

  for (int kt = 0; kt < K; kt += 16) {
    float4 a0 = *(const float4*)(Ap + kt);
    float4 a1 = *(const float4*)(Ap + kt + 8);
    float4 b0 = *(const float4*)(Bp + kt);
    float4 b1 = *(const float4*)(Bp + kt + 8);
    __syncthreads();  // previous iteration's LDS reads complete
    As[lkq + 0][lrow] = a0.x; As[lkq + 1][lrow] = a0.y;
    As[lkq + 2][lrow] = a0.z; As[lkq + 3][lrow] = a0.w;
    As[lkq + 8][lrow] = a1.x; As[lkq + 9][lrow] = a1.y;
    As[lkq +10][lrow] = a1.z; As[lkq +11][lrow] = a1.w;
    Bs[lkq + 0][lrow] = b0.x; Bs[lkq + 1][lrow] = b0.y;
    Bs[lkq + 2][lrow] = b0.z; Bs[lkq + 3][lrow] = b0.w;
    Bs[lkq + 8][lrow] = b1.x; Bs[lkq + 9][lrow] = b1.y;
    Bs[lkq +10][lrow] = b1.z; Bs[lkq +11][lrow] = b1.w;
    __syncthreads();
#pragma unroll
    for (int k = 0; k < 16; ++k) {
      float a[8], b[8];
      *(float4*)&a[0] = *(const float4*)&As[k][ty * 8];
      *(float4*)&a[4] = *(const float4*)&As[k][ty * 8 + 4];
      *(float4*)&b[0] = *(const float4*)&Bs[k][tx * 8];
      *(float4*)&b[4] = *(const float4*)&Bs[k][tx * 8 + 4];
#pragma unroll
      for (int i = 0; i < 8; ++i)
#pragma unroll
        for (int j = 0; j < 8; ++j)
          acc[i][j] = fmaf(a[i], b[j], acc[i][j]);
    }
  }
  float* Cp = C + (size_t)(bm + ty * 8) * N + bn + tx * 8;
#pragma unroll
  for (int i = 0; i < 8; ++i) {
    *(float4*)(Cp + (size_t)i * N)     = *(float4*)&acc[i][0];
    *(float4*)(Cp + (size_t)i * N + 4) = *(float4*)&acc[i][4];
  }
}

// ---------------------------------------------------------------------------
// MsPoE RoPE, in-place on Q and K. Layout [S][H*D]. Head h uses the
// cos/sin of original head (H-1-h) => ratio = 1 + (H-1-h)/16.
// Angle computed in fp32 exactly as the reference (t=pos/ratio; ang=t*inv).
// ---------------------------------------------------------------------------
__global__ __launch_bounds__(256)
void rope_kernel(float* __restrict__ Q, float* __restrict__ Kc,
                 const int* __restrict__ pos_ids, int S) {
  const int row = blockIdx.x * 4 + (threadIdx.x >> 6); // over S*NHEADS
  const int j = threadIdx.x & 63;
  const int s = row >> 5;
  const int h = row & 31;
  const int pos = pos_ids[s];
  const int hr = NHEADS - 1 - h;
  const float ratio = 1.0f + 2.0f * ((float)hr / 32.0f);
  const float t = (float)pos / ratio;
  // inv_freq = 10000^(-2j/128), computed in double then rounded to fp32
  const float inv = (float)exp(-0.143911568312127875 * (double)j);
  const float ang = t * inv;
  float sn, cs;
  sincosf(ang, &sn, &cs);  // accurate (ocml) version, large-arg reduction
  const size_t base = (size_t)s * HIDDEN + (size_t)h * HEADDIM + j;
  const float q0 = Q[base], q1 = Q[base + 64];
  Q[base]      = q0 * cs - q1 * sn;
  Q[base + 64] = q1 * cs + q0 * sn;
  const float k0 = Kc[base], k1 = Kc[base + 64];
  Kc[base]      = k0 * cs - k1 * sn;
  Kc[base + 64] = k1 * cs + k0 * sn;
}

// ---------------------------------------------------------------------------
// Causal flash attention, fp32. One block = (head, 32 q-rows), 4 waves.
// Within a wave: 8 q-rows x 8 lanes/row; each lane owns a 16-float d-chunk.
// K/V tiles (32 rows) staged in LDS with 20-float chunk stride so the
// per-chunk b128 reads hit all 8 bank groups (conflict-free broadcast).
// ---------------------------------------------------------------------------
__global__ __launch_bounds__(256)
void attn_kernel(const float* __restrict__ Q, const float* __restrict__ K,
                 const float* __restrict__ V, float* __restrict__ O, int S) {
  __shared__ float Ks[32][160];
  __shared__ float Vs[32][160];
  const int h = blockIdx.y;
  const int nqb = S >> 5;
  const int qb = nqb - 1 - blockIdx.x;  // biggest blocks first (load balance)
  const int tid = threadIdx.x;
  const int wave = tid >> 6;
  const int lane = tid & 63;
  const int r = lane >> 3;   // q-row within wave
  const int c = lane & 7;    // 16-float chunk index
  const int qrow = qb * 32 + wave * 8 + r;
  const float scale = 0.08838834764831845f;  // 1/sqrt(128)

  float qf[16];
  {
    const float* qp = Q + (size_t)qrow * HIDDEN + h * HEADDIM + c * 16;
#pragma unroll
    for (int i = 0; i < 4; ++i)
      *(float4*)&qf[i * 4] = *(const float4*)(qp + i * 4);
  }
  float o[16];
#pragma unroll
  for (int i = 0; i < 16; ++i) o[i] = 0.f;
  float m = -INFINITY, l = 0.f;

  const int strow = tid >> 3;  // staging row 0..31
  const int stc = tid & 7;
  const int ntiles = qb + 1;
  for (int t0 = 0; t0 < ntiles; ++t0) {
    const int kb = t0 * 32;
    __syncthreads();
    {
      const float* kg = K + (size_t)(kb + strow) * HIDDEN + h * HEADDIM;
      const float* vg = V + (size_t)(kb + strow) * HIDDEN + h * HEADDIM;
#pragma unroll
      for (int jj = 0; jj < 4; ++jj) {
        const int cc = stc + jj * 8;                  // float4 index 0..31
        float4 kv = *(const float4*)(kg + cc * 4);
        float4 vv = *(const float4*)(vg + cc * 4);
        const int off = (cc >> 2) * 20 + (cc & 3) * 4;
        *(float4*)&Ks[strow][off] = kv;
        *(float4*)&Vs[strow][off] = vv;
      }
    }
    __syncthreads();

    float sv[32];
#pragma unroll
    for (int kk = 0; kk < 32; ++kk) {
      const float* kr = &Ks[kk][c * 20];
      float kv[16];
#pragma unroll
      for (int i = 0; i < 4; ++i)
        *(float4*)&kv[i * 4] = *(const float4*)(kr + i * 4);
      float d0 = 0.f, d1 = 0.f, d2 = 0.f, d3 = 0.f;
#pragma unroll
      for (int i = 0; i < 4; ++i) {
        d0 = fmaf(qf[i],      kv[i],      d0);
        d1 = fmaf(qf[4 + i],  kv[4 + i],  d1);
        d2 = fmaf(qf[8 + i],  kv[8 + i],  d2);
        d3 = fmaf(qf[12 + i], kv[12 + i], d3);
      }
      float d = (d0 + d1) + (d2 + d3);
      d += __shfl_xor(d, 1);
      d += __shfl_xor(d, 2);
      d += __shfl_xor(d, 4);
      sv[kk] = (kb + kk <= qrow) ? d * scale : -INFINITY;
    }
    float tmax = -INFINITY;
#pragma unroll
    for (int kk = 0; kk < 32; ++kk) tmax = fmaxf(tmax, sv[kk]);
    const float mnew = fmaxf(m, tmax);
    const float corr = __expf(m - mnew);  // exp(-inf)=0 on first tile
#pragma unroll
    for (int i = 0; i < 16; ++i) o[i] *= corr;
    float psum = 0.f;
#pragma unroll
    for (int kk = 0; kk < 32; ++kk) {
      const float p = __expf(sv[kk] - mnew);
      psum += p;
      const float* vr = &Vs[kk][c * 20];
      float vvv[16];
#pragma unroll
      for (int i = 0; i < 4; ++i)
        *(float4*)&vvv[i * 4] = *(const float4*)(vr + i * 4);
#pragma unroll
      for (int i = 0; i < 16; ++i) o[i] = fmaf(p, vvv[i], o[i]);
    }
    l = l * corr + psum;
    m = mnew;
  }
  const float invl = 1.0f / l;
  float* op = O + (size_t)qrow * HIDDEN + h * HEADDIM + c * 16;
#pragma unroll
  for (int i = 0; i < 4; ++i) {
    float4 ov;
    ov.x = o[i * 4 + 0] * invl;
    ov.y = o[i * 4 + 1] * invl;
    ov.z = o[i * 4 + 2] * invl;
    ov.w = o[i * 4 + 3] * invl;
    *(float4*)(op + i * 4) = ov;
  }
}

// ---------------------------------------------------------------------------
extern "C" void kernel_launch(void* const* d_in, const int* in_sizes, int n_in,
                              void* d_out, int out_size, void* d_ws, size_t ws_size,
                              hipStream_t stream) {
  const float* hs  = (const float*)d_in[0];
  const int*   pos = (const int*)d_in[1];
  const float* wq  = (const float*)d_in[2];
  const float* wk  = (const float*)d_in[3];
  const float* wv  = (const float*)d_in[4];
  const float* wo  = (const float*)d_in[5];
  float* out = (float*)d_out;

  const int S = in_sizes[0] / HIDDEN;          // B=1
  const size_t plane = (size_t)S * HIDDEN;     // elements per [S,HID] plane

  float* q  = (float*)d_ws;                    // ws: Q | K | attn_out (96 MB)
  float* k  = q + plane;
  float* ao = k + plane;
  float* v  = out;                             // V lives in d_out (one plane),
                                               // fully overwritten by final GEMM

  dim3 gblk(256);
  dim3 ggrid(HIDDEN / 128, S / 128);
  gemm_nt<<<ggrid, gblk, 0, stream>>>(hs, wq, q, S, HIDDEN, HIDDEN);
  gemm_nt<<<ggrid, gblk, 0, stream>>>(hs, wk, k, S, HIDDEN, HIDDEN);
  gemm_nt<<<ggrid, gblk, 0, stream>>>(hs, wv, v, S, HIDDEN, HIDDEN);

  rope_kernel<<<(S * NHEADS) / 4, 256, 0, stream>>>(q, k, pos, S);

  attn_kernel<<<dim3(S / 32, NHEADS), 256, 0, stream>>>(q, k, v, ao, S);

  gemm_nt<<<ggrid, gblk, 0, stream>>>(ao, wo, out, S, HIDDEN, HIDDEN);
}

// Round 2
// 4729.184 us; speedup vs baseline: 1.0392x; 1.0392x over previous
//
#include <hip/hip_runtime.h>
#include <math.h>

#define HIDDEN 4096
#define NHEADS 32
#define HEADDIM 128

typedef __attribute__((ext_vector_type(8))) short bf16x8;
typedef __attribute__((ext_vector_type(4))) float f32x4;

#define GLL(g, l) __builtin_amdgcn_global_load_lds( \
    (const __attribute__((address_space(1))) void*)(g), \
    (__attribute__((address_space(3))) void*)(l), 16, 0, 0)

__device__ __forceinline__ unsigned short f2bf(float f) {  // RNE
  unsigned int u = __float_as_uint(f);
  unsigned int r = (u + 0x7FFFu + ((u >> 16) & 1u)) >> 16;
  return (unsigned short)r;
}
__device__ __forceinline__ float bf2f(unsigned short h) {
  return __uint_as_float(((unsigned int)h) << 16);
}

// ---------------------------------------------------------------------------
// Elementwise split: X (fp32) -> hi = bf16(X), lo = bf16(X - hi). 4 elem/thread.
// ---------------------------------------------------------------------------
__global__ __launch_bounds__(256)
void split_bf16(const float* __restrict__ X, unsigned short* __restrict__ H,
                unsigned short* __restrict__ L) {
  const int i = blockIdx.x * 256 + threadIdx.x;
  float4 v = ((const float4*)X)[i];
  ushort4 h, lo;
  const float* vf = (const float*)&v;
  unsigned short* hp = (unsigned short*)&h;
  unsigned short* lp = (unsigned short*)&lo;
#pragma unroll
  for (int j = 0; j < 4; ++j) {
    float f = vf[j];
    unsigned short hb = f2bf(f);
    hp[j] = hb;
    lp[j] = f2bf(f - bf2f(hb));
  }
  ((ushort4*)H)[i] = h;
  ((ushort4*)L)[i] = lo;
}

// ---------------------------------------------------------------------------
// bf16x3 MFMA GEMM (NT): C[M,N] fp32 = (Ahi+Alo)[M,K] . (Bhi+Blo)[N,K]^T
// 128x128 tile, BK=32, 4 waves. LDS: 4 planes x 128x32 bf16 (8KB) = 32KB.
// global_load_lds w16 with pre-swizzled source; XOR chunk swizzle on reads.
// 48 MFMA (16x16x32) per K-step per wave: hi*hi + hi*lo + lo*hi.
// ---------------------------------------------------------------------------
__global__ __launch_bounds__(256)
void gemm_bf16x3(const unsigned short* __restrict__ Ahi, const unsigned short* __restrict__ Alo,
                 const unsigned short* __restrict__ Bhi, const unsigned short* __restrict__ Blo,
                 float* __restrict__ C, int M, int N, int K) {
  __shared__ unsigned short lds[4 * 4096];
  const int tid = threadIdx.x;
  const int bm = blockIdx.y * 128;
  const int bn = blockIdx.x * 128;
  const int w = tid >> 6, l = tid & 63;
  const int wr = (w >> 1) * 64, wc = (w & 1) * 64;
  const int lr = l & 15, lc = l >> 4;

  f32x4 acc[4][4];
#pragma unroll
  for (int m = 0; m < 4; ++m)
#pragma unroll
    for (int n = 0; n < 4; ++n) acc[m][n] = (f32x4){0.f, 0.f, 0.f, 0.f};

  // staging map: LDS 16B-slot p -> tile (row = p>>2, chunk = (p&3)^(row&3))
  const int p0 = tid, p1 = tid + 256;
  const int r0 = p0 >> 2, c0 = (p0 & 3) ^ (r0 & 3);
  const int r1 = p1 >> 2, c1 = (p1 & 3) ^ (r1 & 3);
  const size_t a0 = (size_t)(bm + r0) * K + c0 * 8;
  const size_t a1 = (size_t)(bm + r1) * K + c1 * 8;
  const size_t b0 = (size_t)(bn + r0) * K + c0 * 8;
  const size_t b1 = (size_t)(bn + r1) * K + c1 * 8;
  unsigned short* lp0 = &lds[p0 * 8];
  unsigned short* lp1 = &lds[p1 * 8];

  // fragment read offsets (ushort units), chunk XOR-swizzled
  const int fa = (lc ^ (lr & 3)) * 8;
  int aoff[4], boff[4];
#pragma unroll
  for (int m = 0; m < 4; ++m) aoff[m] = (wr + m * 16 + lr) * 32 + fa;
#pragma unroll
  for (int n = 0; n < 4; ++n) boff[n] = (wc + n * 16 + lr) * 32 + fa;

  for (int kt = 0; kt < K; kt += 32) {
    GLL(Ahi + a0 + kt, lp0);
    GLL(Ahi + a1 + kt, lp1);
    GLL(Alo + a0 + kt, lp0 + 4096);
    GLL(Alo + a1 + kt, lp1 + 4096);
    GLL(Bhi + b0 + kt, lp0 + 8192);
    GLL(Bhi + b1 + kt, lp1 + 8192);
    GLL(Blo + b0 + kt, lp0 + 12288);
    GLL(Blo + b1 + kt, lp1 + 12288);
    __syncthreads();  // drains vmcnt -> LDS tiles ready

    bf16x8 ah[4], al[4], bh[4], bl[4];
#pragma unroll
    for (int m = 0; m < 4; ++m) {
      ah[m] = *(const bf16x8*)&lds[aoff[m]];
      al[m] = *(const bf16x8*)&lds[4096 + aoff[m]];
    }
#pragma unroll
    for (int n = 0; n < 4; ++n) {
      bh[n] = *(const bf16x8*)&lds[8192 + boff[n]];
      bl[n] = *(const bf16x8*)&lds[12288 + boff[n]];
    }
#pragma unroll
    for (int m = 0; m < 4; ++m)
#pragma unroll
      for (int n = 0; n < 4; ++n) {
        acc[m][n] = __builtin_amdgcn_mfma_f32_16x16x32_bf16(ah[m], bh[n], acc[m][n], 0, 0, 0);
        acc[m][n] = __builtin_amdgcn_mfma_f32_16x16x32_bf16(ah[m], bl[n], acc[m][n], 0, 0, 0);
        acc[m][n] = __builtin_amdgcn_mfma_f32_16x16x32_bf16(al[m], bh[n], acc[m][n], 0, 0, 0);
      }
    __syncthreads();  // frag reads done before next stage overwrites
  }

  // epilogue: C/D layout col=lane&15, row=(lane>>4)*4+reg
#pragma unroll
  for (int m = 0; m < 4; ++m) {
    const int row0 = bm + wr + m * 16 + lc * 4;
#pragma unroll
    for (int n = 0; n < 4; ++n) {
      const int col = bn + wc + n * 16 + lr;
      float* cp = C + (size_t)row0 * N + col;
#pragma unroll
      for (int j = 0; j < 4; ++j) cp[(size_t)j * N] = acc[m][n][j];
    }
  }
}

// ---------------------------------------------------------------------------
// fp32 fallback GEMM (round-1 kernel), used only if ws is too small.
// ---------------------------------------------------------------------------
__global__ __launch_bounds__(256)
void gemm_nt(const float* __restrict__ A, const float* __restrict__ B,
             float* __restrict__ C, int M, int N, int K) {
  __shared__ float As[16][128];
  __shared__ float Bs[16][128];
  const int tid = threadIdx.x;
  const int bm = blockIdx.y * 128;
  const int bn = blockIdx.x * 128;
  const int ty = tid >> 4;
  const int tx = tid & 15;
  const int lrow = tid >> 1;
  const int lkq = (tid & 1) * 4;

  float acc[8][8];
#pragma unroll
  for (int i = 0; i < 8; ++i)
#pragma unroll
    for (int j = 0; j < 8; ++j) acc[i][j] = 0.f;

  const float* Ap = A + (size_t)(bm + lrow) * K + lkq;
  const float* Bp = B + (size_t)(bn + lrow) * K + lkq;

  for (int kt = 0; kt < K; kt += 16) {
    float4 a0 = *(const float4*)(Ap + kt);
    float4 a1 = *(const float4*)(Ap + kt + 8);
    float4 b0 = *(const float4*)(Bp + kt);
    float4 b1 = *(const float4*)(Bp + kt + 8);
    __syncthreads();
    As[lkq + 0][lrow] = a0.x; As[lkq + 1][lrow] = a0.y;
    As[lkq + 2][lrow] = a0.z; As[lkq + 3][lrow] = a0.w;
    As[lkq + 8][lrow] = a1.x; As[lkq + 9][lrow] = a1.y;
    As[lkq +10][lrow] = a1.z; As[lkq +11][lrow] = a1.w;
    Bs[lkq + 0][lrow] = b0.x; Bs[lkq + 1][lrow] = b0.y;
    Bs[lkq + 2][lrow] = b0.z; Bs[lkq + 3][lrow] = b0.w;
    Bs[lkq + 8][lrow] = b1.x; Bs[lkq + 9][lrow] = b1.y;
    Bs[lkq +10][lrow] = b1.z; Bs[lkq +11][lrow] = b1.w;
    __syncthreads();
#pragma unroll
    for (int k = 0; k < 16; ++k) {
      float a[8], b[8];
      *(float4*)&a[0] = *(const float4*)&As[k][ty * 8];
      *(float4*)&a[4] = *(const float4*)&As[k][ty * 8 + 4];
      *(float4*)&b[0] = *(const float4*)&Bs[k][tx * 8];
      *(float4*)&b[4] = *(const float4*)&Bs[k][tx * 8 + 4];
#pragma unroll
      for (int i = 0; i < 8; ++i)
#pragma unroll
        for (int j = 0; j < 8; ++j) acc[i][j] = fmaf(a[i], b[j], acc[i][j]);
    }
  }
  float* Cp = C + (size_t)(bm + ty * 8) * N + bn + tx * 8;
#pragma unroll
  for (int i = 0; i < 8; ++i) {
    *(float4*)(Cp + (size_t)i * N) = *(float4*)&acc[i][0];
    *(float4*)(Cp + (size_t)i * N + 4) = *(float4*)&acc[i][4];
  }
}

// ---------------------------------------------------------------------------
// MsPoE RoPE in-place on Q and K (fp32 [S][H*D]); head h uses reversed head
// order ratios. Angle math matches the reference fp32 path.
// ---------------------------------------------------------------------------
__global__ __launch_bounds__(256)
void rope_kernel(float* __restrict__ Q, float* __restrict__ Kc,
                 const int* __restrict__ pos_ids, int S) {
  const int row = blockIdx.x * 4 + (threadIdx.x >> 6);
  const int j = threadIdx.x & 63;
  const int s = row >> 5;
  const int h = row & 31;
  const int pos = pos_ids[s];
  const int hr = NHEADS - 1 - h;
  const float ratio = 1.0f + 2.0f * ((float)hr / 32.0f);
  const float t = (float)pos / ratio;
  const float inv = (float)exp(-0.143911568312127875 * (double)j);
  const float ang = t * inv;
  float sn, cs;
  sincosf(ang, &sn, &cs);
  const size_t base = (size_t)s * HIDDEN + (size_t)h * HEADDIM + j;
  const float q0 = Q[base], q1 = Q[base + 64];
  Q[base] = q0 * cs - q1 * sn;
  Q[base + 64] = q1 * cs + q0 * sn;
  const float k0 = Kc[base], k1 = Kc[base + 64];
  Kc[base] = k0 * cs - k1 * sn;
  Kc[base + 64] = k1 * cs + k0 * sn;
}

// ---------------------------------------------------------------------------
// Causal flash attention, fp32. Block = (head, q-block pair {i, nqb-1-i}) ->
// constant 65 tiles of work per block. Lane owns strided float4s
// (d = c*4 + 32*i): staging writes and compute reads are both bank-uniform.
// K/V staged via register double-buffer (prefetch next tile during compute).
// ---------------------------------------------------------------------------
__global__ __launch_bounds__(256)
void attn_kernel(const float* __restrict__ Q, const float* __restrict__ K,
                 const float* __restrict__ V, float* __restrict__ O, int S) {
  __shared__ float Ks[32 * 128];
  __shared__ float Vs[32 * 128];
  const int h = blockIdx.y;
  const int nqb = S >> 5;
  const int tid = threadIdx.x;
  const int wave = tid >> 6, lane = tid & 63;
  const int r = lane >> 3, c = lane & 7;
  const int strow = tid >> 3, stc = tid & 7;
  const float scale = 0.08838834764831845f;  // 1/sqrt(128)

  for (int half = 0; half < 2; ++half) {
    const int qb = half ? (nqb - 1 - (int)blockIdx.x) : (int)blockIdx.x;
    const int qrow = qb * 32 + wave * 8 + r;
    const float* qp = Q + (size_t)qrow * HIDDEN + h * HEADDIM;
    float qf[16];
#pragma unroll
    for (int i = 0; i < 4; ++i)
      *(float4*)&qf[i * 4] = *(const float4*)(qp + c * 4 + 32 * i);
    float o[16];
#pragma unroll
    for (int i = 0; i < 16; ++i) o[i] = 0.f;
    float m = -INFINITY, l = 0.f;
    const int ntiles = qb + 1;

    const float* kg = K + (size_t)strow * HIDDEN + h * HEADDIM;
    const float* vg = V + (size_t)strow * HIDDEN + h * HEADDIM;
    float4 kreg[4], vreg[4];
#pragma unroll
    for (int jj = 0; jj < 4; ++jj) {  // prefetch tile 0
      kreg[jj] = *(const float4*)(kg + (stc + jj * 8) * 4);
      vreg[jj] = *(const float4*)(vg + (stc + jj * 8) * 4);
    }
    for (int t = 0; t < ntiles; ++t) {
      __syncthreads();  // prev compute done -> LDS writable
#pragma unroll
      for (int jj = 0; jj < 4; ++jj) {
        *(float4*)&Ks[strow * 128 + (stc + jj * 8) * 4] = kreg[jj];
        *(float4*)&Vs[strow * 128 + (stc + jj * 8) * 4] = vreg[jj];
      }
      if (t + 1 < ntiles) {  // prefetch next tile (latency hides under compute)
        const float* kg2 = kg + (size_t)(t + 1) * 32 * HIDDEN;
        const float* vg2 = vg + (size_t)(t + 1) * 32 * HIDDEN;
#pragma unroll
        for (int jj = 0; jj < 4; ++jj) {
          kreg[jj] = *(const float4*)(kg2 + (stc + jj * 8) * 4);
          vreg[jj] = *(const float4*)(vg2 + (stc + jj * 8) * 4);
        }
      }
      __syncthreads();  // LDS tiles visible

      const int kb = t * 32;
      float sv[32];
#pragma unroll
      for (int kk = 0; kk < 32; ++kk) {
        const float* kr = &Ks[kk * 128 + c * 4];
        float kv[16];
#pragma unroll
        for (int i = 0; i < 4; ++i)
          *(float4*)&kv[i * 4] = *(const float4*)(kr + 32 * i);
        float d0 = 0.f, d1 = 0.f, d2 = 0.f, d3 = 0.f;
#pragma unroll
        for (int i = 0; i < 4; ++i) {
          d0 = fmaf(qf[i], kv[i], d0);
          d1 = fmaf(qf[4 + i], kv[4 + i], d1);
          d2 = fmaf(qf[8 + i], kv[8 + i], d2);
          d3 = fmaf(qf[12 + i], kv[12 + i], d3);
        }
        float d = (d0 + d1) + (d2 + d3);
        d += __shfl_xor(d, 1);
        d += __shfl_xor(d, 2);
        d += __shfl_xor(d, 4);
        sv[kk] = (kb + kk <= qrow) ? d * scale : -INFINITY;
      }
      float tmax = -INFINITY;
#pragma unroll
      for (int kk = 0; kk < 32; ++kk) tmax = fmaxf(tmax, sv[kk]);
      const float mnew = fmaxf(m, tmax);
      const float corr = __expf(m - mnew);
#pragma unroll
      for (int i = 0; i < 16; ++i) o[i] *= corr;
      float psum = 0.f;
#pragma unroll
      for (int kk = 0; kk < 32; ++kk) {
        const float p = __expf(sv[kk] - mnew);
        psum += p;
        const float* vr = &Vs[kk * 128 + c * 4];
        float vv[16];
#pragma unroll
        for (int i = 0; i < 4; ++i)
          *(float4*)&vv[i * 4] = *(const float4*)(vr + 32 * i);
#pragma unroll
        for (int i = 0; i < 16; ++i) o[i] = fmaf(p, vv[i], o[i]);
      }
      l = l * corr + psum;
      m = mnew;
    }
    const float invl = 1.0f / l;
    float* op = O + (size_t)qrow * HIDDEN + h * HEADDIM + c * 4;
#pragma unroll
    for (int i = 0; i < 4; ++i) {
      float4 ov;
      ov.x = o[i * 4 + 0] * invl;
      ov.y = o[i * 4 + 1] * invl;
      ov.z = o[i * 4 + 2] * invl;
      ov.w = o[i * 4 + 3] * invl;
      *(float4*)(op + 32 * i) = ov;
    }
  }
}

// ---------------------------------------------------------------------------
extern "C" void kernel_launch(void* const* d_in, const int* in_sizes, int n_in,
                              void* d_out, int out_size, void* d_ws, size_t ws_size,
                              hipStream_t stream) {
  const float* hs = (const float*)d_in[0];
  const int* pos = (const int*)d_in[1];
  const float* wq = (const float*)d_in[2];
  const float* wk = (const float*)d_in[3];
  const float* wv = (const float*)d_in[4];
  const float* wo = (const float*)d_in[5];
  float* out = (float*)d_out;

  const int S = in_sizes[0] / HIDDEN;  // B=1
  const size_t planeF = (size_t)S * HIDDEN * sizeof(float);     // 32MB
  const size_t planeH = (size_t)S * HIDDEN * sizeof(short);     // 16MB
  const size_t wplaneH = (size_t)HIDDEN * HIDDEN * sizeof(short);  // 32MB
  const size_t needed = 3 * planeF + 4 * planeH + 8 * wplaneH;  // ~416MB

  char* wp = (char*)d_ws;
  float* q = (float*)wp;   wp += planeF;
  float* k = (float*)wp;   wp += planeF;
  float* ao = (float*)wp;  wp += planeF;
  float* v = out;  // V plane lives in d_out; final GEMM fully overwrites it

  dim3 mg(HIDDEN / 128, S / 128);
  const int nh = S * HIDDEN;
  const int nw = HIDDEN * HIDDEN;

  if (ws_size >= needed) {
    unsigned short* hs_hi = (unsigned short*)wp;  wp += planeH;
    unsigned short* hs_lo = (unsigned short*)wp;  wp += planeH;
    unsigned short* ao_hi = (unsigned short*)wp;  wp += planeH;
    unsigned short* ao_lo = (unsigned short*)wp;  wp += planeH;
    unsigned short* wqh = (unsigned short*)wp;  wp += wplaneH;
    unsigned short* wql = (unsigned short*)wp;  wp += wplaneH;
    unsigned short* wkh = (unsigned short*)wp;  wp += wplaneH;
    unsigned short* wkl = (unsigned short*)wp;  wp += wplaneH;
    unsigned short* wvh = (unsigned short*)wp;  wp += wplaneH;
    unsigned short* wvl = (unsigned short*)wp;  wp += wplaneH;
    unsigned short* woh = (unsigned short*)wp;  wp += wplaneH;
    unsigned short* wol = (unsigned short*)wp;  wp += wplaneH;

    split_bf16<<<nh / 1024, 256, 0, stream>>>(hs, hs_hi, hs_lo);
    split_bf16<<<nw / 1024, 256, 0, stream>>>(wq, wqh, wql);
    split_bf16<<<nw / 1024, 256, 0, stream>>>(wk, wkh, wkl);
    split_bf16<<<nw / 1024, 256, 0, stream>>>(wv, wvh, wvl);
    split_bf16<<<nw / 1024, 256, 0, stream>>>(wo, woh, wol);

    gemm_bf16x3<<<mg, 256, 0, stream>>>(hs_hi, hs_lo, wqh, wql, q, S, HIDDEN, HIDDEN);
    gemm_bf16x3<<<mg, 256, 0, stream>>>(hs_hi, hs_lo, wkh, wkl, k, S, HIDDEN, HIDDEN);
    gemm_bf16x3<<<mg, 256, 0, stream>>>(hs_hi, hs_lo, wvh, wvl, v, S, HIDDEN, HIDDEN);

    rope_kernel<<<(S * NHEADS) / 4, 256, 0, stream>>>(q, k, pos, S);
    attn_kernel<<<dim3(S / 64, NHEADS), 256, 0, stream>>>(q, k, v, ao, S);

    split_bf16<<<nh / 1024, 256, 0, stream>>>(ao, ao_hi, ao_lo);
    gemm_bf16x3<<<mg, 256, 0, stream>>>(ao_hi, ao_lo, woh, wol, out, S, HIDDEN, HIDDEN);
  } else {
    // fallback: fp32 vector GEMMs (round-1 path, needs only 96MB)
    gemm_nt<<<mg, 256, 0, stream>>>(hs, wq, q, S, HIDDEN, HIDDEN);
    gemm_nt<<<mg, 256, 0, stream>>>(hs, wk, k, S, HIDDEN, HIDDEN);
    gemm_nt<<<mg, 256, 0, stream>>>(hs, wv, v, S, HIDDEN, HIDDEN);
    rope_kernel<<<(S * NHEADS) / 4, 256, 0, stream>>>(q, k, pos, S);
    attn_kernel<<<dim3(S / 64, NHEADS), 256, 0, stream>>>(q, k, v, ao, S);
    gemm_nt<<<mg, 256, 0, stream>>>(ao, wo, out, S, HIDDEN, HIDDEN);
  }
}

// Round 5
// 4458.424 us; speedup vs baseline: 1.1023x; 1.0607x over previous
//
#include <hip/hip_runtime.h>
#include <math.h>

#define HIDDEN 4096
#define NHEADS 32
#define HEADDIM 128

typedef __attribute__((ext_vector_type(8))) short bf16x8;
typedef __attribute__((ext_vector_type(4))) float f32x4;

#define GLL(g, l) __builtin_amdgcn_global_load_lds( \
    (const __attribute__((address_space(1))) void*)(g), \
    (__attribute__((address_space(3))) void*)(l), 16, 0, 0)

__device__ __forceinline__ unsigned short f2bf(float f) {  // RNE
  unsigned int u = __float_as_uint(f);
  unsigned int r = (u + 0x7FFFu + ((u >> 16) & 1u)) >> 16;
  return (unsigned short)r;
}
__device__ __forceinline__ float bf2f(unsigned short h) {
  return __uint_as_float(((unsigned int)h) << 16);
}

// ---------------------------------------------------------------------------
// Elementwise split: X (fp32) -> hi = bf16(X), lo = bf16(X - hi). 4 elem/thread.
// ---------------------------------------------------------------------------
__global__ __launch_bounds__(256)
void split_bf16(const float* __restrict__ X, unsigned short* __restrict__ H,
                unsigned short* __restrict__ L) {
  const int i = blockIdx.x * 256 + threadIdx.x;
  float4 v = ((const float4*)X)[i];
  ushort4 h, lo;
  const float* vf = (const float*)&v;
  unsigned short* hp = (unsigned short*)&h;
  unsigned short* lp = (unsigned short*)&lo;
#pragma unroll
  for (int j = 0; j < 4; ++j) {
    float f = vf[j];
    unsigned short hb = f2bf(f);
    hp[j] = hb;
    lp[j] = f2bf(f - bf2f(hb));
  }
  ((ushort4*)H)[i] = h;
  ((ushort4*)L)[i] = lo;
}

// ---------------------------------------------------------------------------
// bf16x3 MFMA GEMM (NT): C[M,N] fp32 = (Ahi+Alo)[M,K] . (Bhi+Blo)[N,K]^T
// 128x128 tile, BK=32, 4 waves, DOUBLE-BUFFERED LDS (2 x 4 planes x 8KB).
// 2-phase pipeline: __syncthreads (drains prev GLLs) -> issue next-tile GLLs
// -> ds_read + 48 MFMA on current tile. XOR swizzle pos = chunk ^ ((row>>1)&3)
// applied on BOTH staging source and frag reads -> 2-way (free) bank pattern.
// ---------------------------------------------------------------------------
__global__ __launch_bounds__(256)
void gemm_bf16x3(const unsigned short* __restrict__ Ahi, const unsigned short* __restrict__ Alo,
                 const unsigned short* __restrict__ Bhi, const unsigned short* __restrict__ Blo,
                 float* __restrict__ C, int M, int N, int K) {
  __shared__ unsigned short lds[2][4][4096];  // [buf][plane][128*32]
  const int tid = threadIdx.x;
  const int bm = blockIdx.y * 128;
  const int bn = blockIdx.x * 128;
  const int w = tid >> 6, l = tid & 63;
  const int wr = (w >> 1) * 64, wc = (w & 1) * 64;
  const int lr = l & 15, lc = l >> 4;

  f32x4 acc[4][4];
#pragma unroll
  for (int m = 0; m < 4; ++m)
#pragma unroll
    for (int n = 0; n < 4; ++n) acc[m][n] = (f32x4){0.f, 0.f, 0.f, 0.f};

  // staging: slot p -> row = p>>2, fetched chunk = (p&3) ^ ((row>>1)&3)
  const int p0 = tid, p1 = tid + 256;
  const int r0 = p0 >> 2, c0 = (p0 & 3) ^ ((p0 >> 3) & 3);
  const int r1 = p1 >> 2, c1 = (p1 & 3) ^ ((p1 >> 3) & 3);
  const size_t a0 = (size_t)(bm + r0) * K + c0 * 8;
  const size_t a1 = (size_t)(bm + r1) * K + c1 * 8;
  const size_t b0 = (size_t)(bn + r0) * K + c0 * 8;
  const size_t b1 = (size_t)(bn + r1) * K + c1 * 8;

  // fragment read offsets (ushort units), same swizzle
  const int pos = (lc ^ ((lr >> 1) & 3)) * 8;
  int aoff[4], boff[4];
#pragma unroll
  for (int m = 0; m < 4; ++m) aoff[m] = (wr + m * 16 + lr) * 32 + pos;
#pragma unroll
  for (int n = 0; n < 4; ++n) boff[n] = (wc + n * 16 + lr) * 32 + pos;

#define STAGE(b, kt)                                  \
  do {                                                \
    unsigned short* Lb = &lds[(b)][0][0];             \
    GLL(Ahi + a0 + (kt), Lb + p0 * 8);                \
    GLL(Ahi + a1 + (kt), Lb + p1 * 8);                \
    GLL(Alo + a0 + (kt), Lb + 4096 + p0 * 8);         \
    GLL(Alo + a1 + (kt), Lb + 4096 + p1 * 8);         \
    GLL(Bhi + b0 + (kt), Lb + 8192 + p0 * 8);         \
    GLL(Bhi + b1 + (kt), Lb + 8192 + p1 * 8);         \
    GLL(Blo + b0 + (kt), Lb + 12288 + p0 * 8);        \
    GLL(Blo + b1 + (kt), Lb + 12288 + p1 * 8);        \
  } while (0)

  STAGE(0, 0);
  for (int kt = 0; kt < K; kt += 32) {
    const int b = (kt >> 5) & 1;
    __syncthreads();  // implicit vmcnt(0): tile b ready; all waves done with b^1
    if (kt + 32 < K) STAGE(b ^ 1, kt + 32);
    const unsigned short* Lb = &lds[b][0][0];
    bf16x8 ah[4], al[4], bh[4], bl[4];
#pragma unroll
    for (int m = 0; m < 4; ++m) {
      ah[m] = *(const bf16x8*)(Lb + aoff[m]);
      al[m] = *(const bf16x8*)(Lb + 4096 + aoff[m]);
    }
#pragma unroll
    for (int n = 0; n < 4; ++n) {
      bh[n] = *(const bf16x8*)(Lb + 8192 + boff[n]);
      bl[n] = *(const bf16x8*)(Lb + 12288 + boff[n]);
    }
#pragma unroll
    for (int m = 0; m < 4; ++m)
#pragma unroll
      for (int n = 0; n < 4; ++n) {
        acc[m][n] = __builtin_amdgcn_mfma_f32_16x16x32_bf16(ah[m], bh[n], acc[m][n], 0, 0, 0);
        acc[m][n] = __builtin_amdgcn_mfma_f32_16x16x32_bf16(ah[m], bl[n], acc[m][n], 0, 0, 0);
        acc[m][n] = __builtin_amdgcn_mfma_f32_16x16x32_bf16(al[m], bh[n], acc[m][n], 0, 0, 0);
      }
  }
#undef STAGE

  // epilogue: C/D layout col=lane&15, row=(lane>>4)*4+reg
#pragma unroll
  for (int m = 0; m < 4; ++m) {
    const int row0 = bm + wr + m * 16 + lc * 4;
#pragma unroll
    for (int n = 0; n < 4; ++n) {
      const int col = bn + wc + n * 16 + lr;
      float* cp = C + (size_t)row0 * N + col;
#pragma unroll
      for (int j = 0; j < 4; ++j) cp[(size_t)j * N] = acc[m][n][j];
    }
  }
}

// ---------------------------------------------------------------------------
// fp32 fallback GEMM (round-1 kernel), used only if ws is too small.
// ---------------------------------------------------------------------------
__global__ __launch_bounds__(256)
void gemm_nt(const float* __restrict__ A, const float* __restrict__ B,
             float* __restrict__ C, int M, int N, int K) {
  __shared__ float As[16][128];
  __shared__ float Bs[16][128];
  const int tid = threadIdx.x;
  const int bm = blockIdx.y * 128;
  const int bn = blockIdx.x * 128;
  const int ty = tid >> 4;
  const int tx = tid & 15;
  const int lrow = tid >> 1;
  const int lkq = (tid & 1) * 4;

  float acc[8][8];
#pragma unroll
  for (int i = 0; i < 8; ++i)
#pragma unroll
    for (int j = 0; j < 8; ++j) acc[i][j] = 0.f;

  const float* Ap = A + (size_t)(bm + lrow) * K + lkq;
  const float* Bp = B + (size_t)(bn + lrow) * K + lkq;

  for (int kt = 0; kt < K; kt += 16) {
    float4 a0 = *(const float4*)(Ap + kt);
    float4 a1 = *(const float4*)(Ap + kt + 8);
    float4 b0 = *(const float4*)(Bp + kt);
    float4 b1 = *(const float4*)(Bp + kt + 8);
    __syncthreads();
    As[lkq + 0][lrow] = a0.x; As[lkq + 1][lrow] = a0.y;
    As[lkq + 2][lrow] = a0.z; As[lkq + 3][lrow] = a0.w;
    As[lkq + 8][lrow] = a1.x; As[lkq + 9][lrow] = a1.y;
    As[lkq +10][lrow] = a1.z; As[lkq +11][lrow] = a1.w;
    Bs[lkq + 0][lrow] = b0.x; Bs[lkq + 1][lrow] = b0.y;
    Bs[lkq + 2][lrow] = b0.z; Bs[lkq + 3][lrow] = b0.w;
    Bs[lkq + 8][lrow] = b1.x; Bs[lkq + 9][lrow] = b1.y;
    Bs[lkq +10][lrow] = b1.z; Bs[lkq +11][lrow] = b1.w;
    __syncthreads();
#pragma unroll
    for (int k = 0; k < 16; ++k) {
      float a[8], b[8];
      *(float4*)&a[0] = *(const float4*)&As[k][ty * 8];
      *(float4*)&a[4] = *(const float4*)&As[k][ty * 8 + 4];
      *(float4*)&b[0] = *(const float4*)&Bs[k][tx * 8];
      *(float4*)&b[4] = *(const float4*)&Bs[k][tx * 8 + 4];
#pragma unroll
      for (int i = 0; i < 8; ++i)
#pragma unroll
        for (int j = 0; j < 8; ++j) acc[i][j] = fmaf(a[i], b[j], acc[i][j]);
    }
  }
  float* Cp = C + (size_t)(bm + ty * 8) * N + bn + tx * 8;
#pragma unroll
  for (int i = 0; i < 8; ++i) {
    *(float4*)(Cp + (size_t)i * N) = *(float4*)&acc[i][0];
    *(float4*)(Cp + (size_t)i * N + 4) = *(float4*)&acc[i][4];
  }
}

// ---------------------------------------------------------------------------
// MsPoE RoPE in-place on Q and K (fp32 [S][H*D]); reversed head order.
// ---------------------------------------------------------------------------
__global__ __launch_bounds__(256)
void rope_kernel(float* __restrict__ Q, float* __restrict__ Kc,
                 const int* __restrict__ pos_ids, int S) {
  const int row = blockIdx.x * 4 + (threadIdx.x >> 6);
  const int j = threadIdx.x & 63;
  const int s = row >> 5;
  const int h = row & 31;
  const int pos = pos_ids[s];
  const int hr = NHEADS - 1 - h;
  const float ratio = 1.0f + 2.0f * ((float)hr / 32.0f);
  const float t = (float)pos / ratio;
  const float inv = (float)exp(-0.143911568312127875 * (double)j);
  const float ang = t * inv;
  float sn, cs;
  sincosf(ang, &sn, &cs);
  const size_t base = (size_t)s * HIDDEN + (size_t)h * HEADDIM + j;
  const float q0 = Q[base], q1 = Q[base + 64];
  Q[base] = q0 * cs - q1 * sn;
  Q[base + 64] = q1 * cs + q0 * sn;
  const float k0 = Kc[base], k1 = Kc[base + 64];
  Kc[base] = k0 * cs - k1 * sn;
  Kc[base + 64] = k1 * cs + k0 * sn;
}

// ---------------------------------------------------------------------------
// Causal flash attention, fp32. Block = (head, q-block pair {i, nqb-1-i}).
// K/V staged via global_load_lds (zero VGPR cost) into double-buffered LDS;
// stage(t+1) issued right after the barrier, hides under compute(t).
// Reads are bank-uniform (broadcast rows, 8 chunks x 4 banks). No register
// prefetch -> no spills (round-2 post-mortem: spill traffic 1.8 GB).
// ---------------------------------------------------------------------------
__global__ __launch_bounds__(256)
void attn_kernel(const float* __restrict__ Q, const float* __restrict__ K,
                 const float* __restrict__ V, float* __restrict__ O, int S) {
  __shared__ float Ks[2][32 * 128];
  __shared__ float Vs[2][32 * 128];
  const int h = blockIdx.y;
  const int nqb = S >> 5;
  const int tid = threadIdx.x;
  const int wave = tid >> 6, lane = tid & 63;
  const int r = lane >> 3, c = lane & 7;
  const float scale = 0.08838834764831845f;  // 1/sqrt(128)
  const float* Kh = K + (size_t)h * HEADDIM;
  const float* Vh = V + (size_t)h * HEADDIM;

#define ASTAGE(b, kb)                                                        \
  do {                                                                       \
    _Pragma("unroll")                                                        \
    for (int i = 0; i < 4; ++i) {                                            \
      const int p = i * 256 + tid;                                           \
      const int row = p >> 5, c4 = p & 31;                                   \
      GLL(Kh + (size_t)((kb) + row) * HIDDEN + c4 * 4, &Ks[(b)][p * 4]);     \
      GLL(Vh + (size_t)((kb) + row) * HIDDEN + c4 * 4, &Vs[(b)][p * 4]);     \
    }                                                                        \
  } while (0)

  for (int half = 0; half < 2; ++half) {
    const int qb = half ? (nqb - 1 - (int)blockIdx.x) : (int)blockIdx.x;
    const int qrow = qb * 32 + wave * 8 + r;
    const float* qp = Q + (size_t)qrow * HIDDEN + h * HEADDIM;
    float qf[16];
#pragma unroll
    for (int i = 0; i < 4; ++i)
      *(float4*)&qf[i * 4] = *(const float4*)(qp + c * 4 + 32 * i);
    float o[16];
#pragma unroll
    for (int i = 0; i < 16; ++i) o[i] = 0.f;
    float m = -INFINITY, lsum = 0.f;
    const int nt = qb + 1;

    __syncthreads();  // all waves done with previous half's LDS reads
    ASTAGE(0, 0);
    for (int t = 0; t < nt; ++t) {
      __syncthreads();  // implicit vmcnt(0): tile t landed; buf t^1 free
      if (t + 1 < nt) ASTAGE((t + 1) & 1, (t + 1) * 32);
      const float* Kb = Ks[t & 1];
      const float* Vb = Vs[t & 1];
      const int kb = t * 32;

      float sv[32];
#pragma unroll
      for (int kk = 0; kk < 32; ++kk) {
        const float* kr = Kb + kk * 128 + c * 4;
        float kv[16];
#pragma unroll
        for (int i = 0; i < 4; ++i)
          *(float4*)&kv[i * 4] = *(const float4*)(kr + 32 * i);
        float d0 = 0.f, d1 = 0.f, d2 = 0.f, d3 = 0.f;
#pragma unroll
        for (int i = 0; i < 4; ++i) {
          d0 = fmaf(qf[i], kv[i], d0);
          d1 = fmaf(qf[4 + i], kv[4 + i], d1);
          d2 = fmaf(qf[8 + i], kv[8 + i], d2);
          d3 = fmaf(qf[12 + i], kv[12 + i], d3);
        }
        float d = (d0 + d1) + (d2 + d3);
        d += __shfl_xor(d, 1);
        d += __shfl_xor(d, 2);
        d += __shfl_xor(d, 4);
        sv[kk] = (kb + kk <= qrow) ? d * scale : -INFINITY;
      }
      float tmax = -INFINITY;
#pragma unroll
      for (int kk = 0; kk < 32; ++kk) tmax = fmaxf(tmax, sv[kk]);
      const float mnew = fmaxf(m, tmax);
      const float corr = __expf(m - mnew);
#pragma unroll
      for (int i = 0; i < 16; ++i) o[i] *= corr;
      float psum = 0.f;
#pragma unroll
      for (int kk = 0; kk < 32; ++kk) {
        const float p = __expf(sv[kk] - mnew);
        psum += p;
        const float* vr = Vb + kk * 128 + c * 4;
        float vv[16];
#pragma unroll
        for (int i = 0; i < 4; ++i)
          *(float4*)&vv[i * 4] = *(const float4*)(vr + 32 * i);
#pragma unroll
        for (int i = 0; i < 16; ++i) o[i] = fmaf(p, vv[i], o[i]);
      }
      lsum = lsum * corr + psum;
      m = mnew;
    }
    const float invl = 1.0f / lsum;
    float* op = O + (size_t)qrow * HIDDEN + h * HEADDIM + c * 4;
#pragma unroll
    for (int i = 0; i < 4; ++i) {
      float4 ov;
      ov.x = o[i * 4 + 0] * invl;
      ov.y = o[i * 4 + 1] * invl;
      ov.z = o[i * 4 + 2] * invl;
      ov.w = o[i * 4 + 3] * invl;
      *(float4*)(op + 32 * i) = ov;
    }
  }
#undef ASTAGE
}

// ---------------------------------------------------------------------------
extern "C" void kernel_launch(void* const* d_in, const int* in_sizes, int n_in,
                              void* d_out, int out_size, void* d_ws, size_t ws_size,
                              hipStream_t stream) {
  const float* hs = (const float*)d_in[0];
  const int* pos = (const int*)d_in[1];
  const float* wq = (const float*)d_in[2];
  const float* wk = (const float*)d_in[3];
  const float* wv = (const float*)d_in[4];
  const float* wo = (const float*)d_in[5];
  float* out = (float*)d_out;

  const int S = in_sizes[0] / HIDDEN;  // B=1
  const size_t planeF = (size_t)S * HIDDEN * sizeof(float);        // 32MB
  const size_t planeH = (size_t)S * HIDDEN * sizeof(short);        // 16MB
  const size_t wplaneH = (size_t)HIDDEN * HIDDEN * sizeof(short);  // 32MB
  const size_t needed = 3 * planeF + 4 * planeH + 8 * wplaneH;     // ~416MB

  char* wp = (char*)d_ws;
  float* q = (float*)wp;   wp += planeF;
  float* k = (float*)wp;   wp += planeF;
  float* ao = (float*)wp;  wp += planeF;
  float* v = out;  // V plane lives in d_out; final GEMM fully overwrites it

  dim3 mg(HIDDEN / 128, S / 128);
  const int nh = S * HIDDEN;
  const int nw = HIDDEN * HIDDEN;

  if (ws_size >= needed) {
    unsigned short* hs_hi = (unsigned short*)wp;  wp += planeH;
    unsigned short* hs_lo = (unsigned short*)wp;  wp += planeH;
    unsigned short* ao_hi = (unsigned short*)wp;  wp += planeH;
    unsigned short* ao_lo = (unsigned short*)wp;  wp += planeH;
    unsigned short* wqh = (unsigned short*)wp;  wp += wplaneH;
    unsigned short* wql = (unsigned short*)wp;  wp += wplaneH;
    unsigned short* wkh = (unsigned short*)wp;  wp += wplaneH;
    unsigned short* wkl = (unsigned short*)wp;  wp += wplaneH;
    unsigned short* wvh = (unsigned short*)wp;  wp += wplaneH;
    unsigned short* wvl = (unsigned short*)wp;  wp += wplaneH;
    unsigned short* woh = (unsigned short*)wp;  wp += wplaneH;
    unsigned short* wol = (unsigned short*)wp;  wp += wplaneH;

    split_bf16<<<nh / 1024, 256, 0, stream>>>(hs, hs_hi, hs_lo);
    split_bf16<<<nw / 1024, 256, 0, stream>>>(wq, wqh, wql);
    split_bf16<<<nw / 1024, 256, 0, stream>>>(wk, wkh, wkl);
    split_bf16<<<nw / 1024, 256, 0, stream>>>(wv, wvh, wvl);
    split_bf16<<<nw / 1024, 256, 0, stream>>>(wo, woh, wol);

    gemm_bf16x3<<<mg, 256, 0, stream>>>(hs_hi, hs_lo, wqh, wql, q, S, HIDDEN, HIDDEN);
    gemm_bf16x3<<<mg, 256, 0, stream>>>(hs_hi, hs_lo, wkh, wkl, k, S, HIDDEN, HIDDEN);
    gemm_bf16x3<<<mg, 256, 0, stream>>>(hs_hi, hs_lo, wvh, wvl, v, S, HIDDEN, HIDDEN);

    rope_kernel<<<(S * NHEADS) / 4, 256, 0, stream>>>(q, k, pos, S);
    attn_kernel<<<dim3(S / 64, NHEADS), 256, 0, stream>>>(q, k, v, ao, S);

    split_bf16<<<nh / 1024, 256, 0, stream>>>(ao, ao_hi, ao_lo);
    gemm_bf16x3<<<mg, 256, 0, stream>>>(ao_hi, ao_lo, woh, wol, out, S, HIDDEN, HIDDEN);
  } else {
    gemm_nt<<<mg, 256, 0, stream>>>(hs, wq, q, S, HIDDEN, HIDDEN);
    gemm_nt<<<mg, 256, 0, stream>>>(hs, wk, k, S, HIDDEN, HIDDEN);
    gemm_nt<<<mg, 256, 0, stream>>>(hs, wv, v, S, HIDDEN, HIDDEN);
    rope_kernel<<<(S * NHEADS) / 4, 256, 0, stream>>>(q, k, pos, S);
    attn_kernel<<<dim3(S / 64, NHEADS), 256, 0, stream>>>(q, k, v, ao, S);
    gemm_nt<<<mg, 256, 0, stream>>>(ao, wo, out, S, HIDDEN, HIDDEN);
  }
}